// Round 1
// baseline (556.054 us; speedup 1.0000x reference)
//
#include <hip/hip_runtime.h>
#include <hip/hip_bf16.h>
#include <math.h>

// Problem constants
#define B_      4
#define S_      512
#define H_      768
#define NH_     4
#define DH_     192
#define N_      4096          // spans per batch
#define WD_     64
#define INNER_  3072
#define INDIM_  1600
#define SP1     513           // S+1 (CLS prepended)
#define ROWS_X  (B_*SP1)      // 2052
#define NSPAN   (B_*N_)       // 16384

typedef __attribute__((ext_vector_type(8))) short bf16x8;
typedef __attribute__((ext_vector_type(4))) float f32x4;

__device__ __forceinline__ unsigned short f2bf(float f){
    unsigned u = __builtin_bit_cast(unsigned, f);
    u = u + 0x7FFFu + ((u >> 16) & 1u);   // round-to-nearest-even
    return (unsigned short)(u >> 16);
}

// ---------------------------------------------------------------------------
// 0. span_masks encoding detection: flag=0 -> 4-byte elems (int32/f32),
//    flag=1 -> 1-byte bools. Scans first 4096 words (16KB, safe either way).
// ---------------------------------------------------------------------------
__global__ void detect_mask_kernel(const unsigned* __restrict__ masks, int* __restrict__ flag){
    __shared__ int s_any;
    if (threadIdx.x == 0) s_any = 0;
    __syncthreads();
    int any = 0;
    for (int i = threadIdx.x; i < 4096; i += 256){
        unsigned v = masks[i];
        if (!(v == 0u || v == 1u || v == 0x3F800000u)) any = 1;
    }
    if (any) s_any = 1;                  // benign race
    __syncthreads();
    if (threadIdx.x == 0) *flag = s_any;
}

// ---------------------------------------------------------------------------
// 1. f32 -> bf16 conversion (n must be multiple of 4)
// ---------------------------------------------------------------------------
__global__ void conv_f32_bf16(const float* __restrict__ in, unsigned short* __restrict__ out, long n4){
    long i = (long)blockIdx.x * blockDim.x + threadIdx.x;
    long stride = (long)gridDim.x * blockDim.x;
    for (; i < n4; i += stride){
        float4 v = ((const float4*)in)[i];
        ushort4 o;
        o.x = f2bf(v.x); o.y = f2bf(v.y); o.z = f2bf(v.z); o.w = f2bf(v.w);
        ((ushort4*)out)[i] = o;
    }
}

// ---------------------------------------------------------------------------
// 2. Build X = [cls_embedding; token_reps] per batch, as bf16. rows = B*(S+1)
// ---------------------------------------------------------------------------
__global__ void build_x_kernel(const float* __restrict__ tok, const float* __restrict__ clsemb,
                               unsigned short* __restrict__ X){
    int r = blockIdx.x;            // 0..2051
    int b = r / SP1, s = r % SP1;
    const float* src = (s == 0) ? clsemb : &tok[((long)b * S_ + (s - 1)) * H_];
    for (int d = threadIdx.x; d < H_; d += 256)
        X[(long)r * H_ + d] = f2bf(src[d]);
}

// ---------------------------------------------------------------------------
// 3. q = cls_embedding @ wq.T + bq   (768 outputs, f32)
// ---------------------------------------------------------------------------
__global__ void q_kernel(const float* __restrict__ clsemb, const float* __restrict__ w,
                         const float* __restrict__ bias, float* __restrict__ q){
    int j = blockIdx.x * 256 + threadIdx.x;
    if (j >= H_) return;
    const float* wr = &w[(long)j * H_];
    float s = bias[j];
    for (int k = 0; k < H_; ++k) s += clsemb[k] * wr[k];
    q[j] = s;
}

// ---------------------------------------------------------------------------
// 4. base_scores[b][h][s] = (q[h,:] . kh[b,s,h,:]) * scale     (f32)
//    KV layout: row r=b*513+s, 1536 wide: [0:768)=k, [768:1536)=v
// ---------------------------------------------------------------------------
__global__ void scores_kernel(const float* __restrict__ q, const float* __restrict__ KV,
                              float* __restrict__ SC){
    int r = blockIdx.x;                       // b*513 + s
    int h = threadIdx.x >> 6, lane = threadIdx.x & 63;
    const float* krow = &KV[(long)r * 1536 + h * DH_];
    const float* qh   = &q[h * DH_];
    float p = 0.f;
    #pragma unroll
    for (int i = 0; i < 3; ++i) p += qh[lane + 64*i] * krow[lane + 64*i];
    #pragma unroll
    for (int off = 32; off > 0; off >>= 1) p += __shfl_down(p, off);
    if (lane == 0){
        const float scale = 0.0721687836487032f;   // 1/sqrt(192)
        SC[((r / SP1) * NH_ + h) * SP1 + (r % SP1)] = p * scale;
    }
}

// ---------------------------------------------------------------------------
// 5. Per-span attention: softmax over {CLS} U [start,end) (<=9 keys), ctx -> bf16
// ---------------------------------------------------------------------------
__global__ __launch_bounds__(256) void attn_kernel(
    const int* __restrict__ span_ids, const void* __restrict__ masks,
    const int* __restrict__ flag, const float* __restrict__ SC,
    const float* __restrict__ KV, unsigned short* __restrict__ CTX)
{
    int blk = blockIdx.x;
    int b = blk >> 12, n = blk & (N_ - 1);
    int t = threadIdx.x;
    __shared__ float w_sh[NH_][9];
    __shared__ int info[2];

    if (t == 0){
        long idx = (long)b * N_ + n;
        int start = span_ids[idx * 2 + 0];
        int end   = span_ids[idx * 2 + 1];
        bool sm = (*flag == 0) ? (((const unsigned*)masks)[idx] != 0u)
                               : (((const unsigned char*)masks)[idx] != 0);
        int cnt = sm ? (end - start) : 0;
        if (cnt < 0) cnt = 0;
        if (cnt > 8) cnt = 8;
        if (start < 0) start = 0;
        if (start + cnt > S_) cnt = S_ - start;
        info[0] = start; info[1] = cnt;
    }
    __syncthreads();
    int start = info[0], cnt = info[1];

    if (t < NH_){
        int h = t;
        const float* sc = &SC[((long)b * NH_ + h) * SP1];
        float m = sc[0];
        for (int j = 0; j < cnt; ++j) m = fmaxf(m, sc[1 + start + j]);
        float e0 = expf(sc[0] - m), sum = e0;
        float ej[8];
        for (int j = 0; j < cnt; ++j){ ej[j] = expf(sc[1 + start + j] - m); sum += ej[j]; }
        float inv = 1.f / sum;
        w_sh[h][0] = e0 * inv;
        for (int j = 0; j < cnt; ++j) w_sh[h][1 + j] = ej[j] * inv;
    }
    __syncthreads();

    long ctxbase = ((long)b * N_ + n) * H_;
    const float* V = &KV[(long)(b * SP1) * 1536 + H_];   // v part of row b*513+0
    #pragma unroll
    for (int i = 0; i < 3; ++i){
        int d = t + 256 * i;
        int h = d / DH_;
        float a = w_sh[h][0] * V[d];                       // CLS row
        for (int j = 0; j < cnt; ++j)
            a += w_sh[h][1 + j] * V[(long)(1 + start + j) * 1536 + d];
        CTX[ctxbase + d] = f2bf(a);
    }
}

// ---------------------------------------------------------------------------
// 6. Fill FEATS columns 768..1599: width_emb (64) + cls_reps (768), bf16
// ---------------------------------------------------------------------------
__global__ void feats_fill_kernel(const int* __restrict__ widths, const float* __restrict__ wtab,
                                  const float* __restrict__ cls_reps, unsigned short* __restrict__ FE){
    int blk = blockIdx.x;
    int b = blk >> 12, n = blk & (N_ - 1);
    int t = threadIdx.x;
    long row = (long)b * N_ + n;
    long base = row * INDIM_;
    if (t < WD_){
        int wd = widths[row];
        if (wd < 0) wd = 0; if (wd > 8) wd = 8;
        FE[base + H_ + t] = f2bf(wtab[wd * WD_ + t]);
    }
    #pragma unroll
    for (int i = 0; i < 3; ++i){
        int d = t + 256 * i;
        FE[base + H_ + WD_ + d] = f2bf(cls_reps[(long)b * H_ + d]);
    }
}

// ---------------------------------------------------------------------------
// 7. bf16 MFMA GEMM: C(MxN) = A(MxK) @ B(NxK)^T + bias, f32 accumulate.
//    128x128 tile, BK=32, 4 waves, padded LDS (K-pad 8 -> 80B row stride).
//    Requires N%128==0, K%32==0. M guarded.
// ---------------------------------------------------------------------------
template<bool RELU, bool OUT_BF16>
__global__ __launch_bounds__(256, 2) void gemm_bf16_kernel(
    const unsigned short* __restrict__ A, const unsigned short* __restrict__ Bm,
    const float* __restrict__ bias, void* __restrict__ Cp,
    int M, int N, int K, int ldc)
{
    __shared__ unsigned short As[128][40];
    __shared__ unsigned short Bs[128][40];
    const int t    = threadIdx.x;
    const int lane = t & 63;
    const int wave = t >> 6;
    const int wr   = wave >> 1, wc = wave & 1;
    const int m0   = blockIdx.y * 128;
    const int n0   = blockIdx.x * 128;

    f32x4 acc[4][4];
    #pragma unroll
    for (int i = 0; i < 4; ++i)
        #pragma unroll
        for (int j = 0; j < 4; ++j)
            acc[i][j] = (f32x4){0.f, 0.f, 0.f, 0.f};

    const int crow0 = t >> 2;          // 0..63
    const int ckoff = (t & 3) * 8;     // 0,8,16,24

    for (int k0 = 0; k0 < K; k0 += 32){
        #pragma unroll
        for (int half = 0; half < 2; ++half){
            int row  = crow0 + half * 64;
            int grow = m0 + row;
            float4 va = make_float4(0.f, 0.f, 0.f, 0.f);
            if (grow < M) va = *(const float4*)&A[(long)grow * K + k0 + ckoff];
            *(float4*)&As[row][ckoff] = va;
            int nrow = n0 + row;       // always < N (N%128==0)
            float4 vb = *(const float4*)&Bm[(long)nrow * K + k0 + ckoff];
            *(float4*)&Bs[row][ckoff] = vb;
        }
        __syncthreads();

        bf16x8 af[4], bfr[4];
        #pragma unroll
        for (int f = 0; f < 4; ++f){
            af[f]  = *(const bf16x8*)&As[wr * 64 + f * 16 + (lane & 15)][(lane >> 4) * 8];
            bfr[f] = *(const bf16x8*)&Bs[wc * 64 + f * 16 + (lane & 15)][(lane >> 4) * 8];
        }
        #pragma unroll
        for (int i = 0; i < 4; ++i)
            #pragma unroll
            for (int j = 0; j < 4; ++j)
                acc[i][j] = __builtin_amdgcn_mfma_f32_16x16x32_bf16(af[i], bfr[j], acc[i][j], 0, 0, 0);
        __syncthreads();
    }

    const int r0 = (lane >> 4) * 4;
    const int cc = lane & 15;
    #pragma unroll
    for (int i = 0; i < 4; ++i){
        #pragma unroll
        for (int j = 0; j < 4; ++j){
            int col = n0 + wc * 64 + j * 16 + cc;
            float bv = bias ? bias[col] : 0.f;
            #pragma unroll
            for (int r = 0; r < 4; ++r){
                int row = m0 + wr * 64 + i * 16 + r0 + r;
                if (row < M){
                    float v = acc[i][j][r] + bv;
                    if (RELU) v = fmaxf(v, 0.f);
                    if (OUT_BF16) ((unsigned short*)Cp)[(long)row * ldc + col] = f2bf(v);
                    else          ((float*)Cp)[(long)row * ldc + col] = v;
                }
            }
        }
    }
}

// ---------------------------------------------------------------------------
extern "C" void kernel_launch(void* const* d_in, const int* in_sizes, int n_in,
                              void* d_out, int out_size, void* d_ws, size_t ws_size,
                              hipStream_t stream)
{
    const float* token_reps  = (const float*)d_in[0];
    const int*   span_ids    = (const int*)d_in[1];
    const void*  span_masks  = d_in[2];
    const float* cls_reps    = (const float*)d_in[3];
    const int*   span_widths = (const int*)d_in[4];
    const float* cls_emb     = (const float*)d_in[5];
    const float* in_proj_w   = (const float*)d_in[6];
    const float* in_proj_b   = (const float*)d_in[7];
    const float* out_proj_w  = (const float*)d_in[8];
    const float* out_proj_b  = (const float*)d_in[9];
    const float* width_table = (const float*)d_in[10];
    const float* w1          = (const float*)d_in[11];
    const float* b1          = (const float*)d_in[12];
    const float* w2          = (const float*)d_in[13];
    const float* b2          = (const float*)d_in[14];

    char* ws = (char*)d_ws;
    size_t off = 0;
    auto alloc = [&](size_t bytes)->char*{
        char* p = ws + off;
        off += (bytes + 255) & ~(size_t)255;
        return p;
    };
    int*            flag = (int*)           alloc(4);
    float*          qbuf = (float*)         alloc((size_t)H_ * 4);
    unsigned short* Xb   = (unsigned short*)alloc((size_t)ROWS_X * H_ * 2);
    unsigned short* Wkv  = (unsigned short*)alloc((size_t)1536 * H_ * 2);
    float*          KV   = (float*)         alloc((size_t)ROWS_X * 1536 * 4);
    float*          SC   = (float*)         alloc((size_t)B_ * NH_ * SP1 * 4);
    unsigned short* CTX  = (unsigned short*)alloc((size_t)NSPAN * H_ * 2);
    unsigned short* Wout = (unsigned short*)alloc((size_t)H_ * H_ * 2);
    unsigned short* FE   = (unsigned short*)alloc((size_t)NSPAN * INDIM_ * 2);
    unsigned short* W1b  = (unsigned short*)alloc((size_t)INNER_ * INDIM_ * 2);
    unsigned short* H1   = (unsigned short*)alloc((size_t)NSPAN * INNER_ * 2);
    unsigned short* W2b  = (unsigned short*)alloc((size_t)H_ * INNER_ * 2);
    (void)ws_size; (void)in_sizes; (void)n_in; (void)out_size;

    // prep
    detect_mask_kernel<<<1, 256, 0, stream>>>((const unsigned*)span_masks, flag);
    build_x_kernel<<<ROWS_X, 256, 0, stream>>>(token_reps, cls_emb, Xb);
    conv_f32_bf16<<<512,  256, 0, stream>>>(in_proj_w + (size_t)768 * H_, Wkv, (long)(1536 * H_ / 4));
    conv_f32_bf16<<<512,  256, 0, stream>>>(out_proj_w, Wout, (long)(H_ * H_ / 4));
    conv_f32_bf16<<<1024, 256, 0, stream>>>(w1, W1b, (long)(INNER_ * INDIM_ / 4));
    conv_f32_bf16<<<1024, 256, 0, stream>>>(w2, W2b, (long)(H_ * INNER_ / 4));
    q_kernel<<<3, 256, 0, stream>>>(cls_emb, in_proj_w, in_proj_b, qbuf);

    // KV = X @ [wk;wv]^T + b   -> f32 (2052 x 1536)
    gemm_bf16_kernel<false,false><<<dim3(1536/128, (ROWS_X + 127)/128), 256, 0, stream>>>(
        Xb, Wkv, in_proj_b + 768, KV, ROWS_X, 1536, H_, 1536);

    scores_kernel<<<ROWS_X, 256, 0, stream>>>(qbuf, KV, SC);
    attn_kernel<<<NSPAN, 256, 0, stream>>>(span_ids, span_masks, flag, SC, KV, CTX);

    // span_reps = CTX @ out_proj^T + b  -> bf16 into FEATS cols [0,768)
    gemm_bf16_kernel<false,true><<<dim3(768/128, NSPAN/128), 256, 0, stream>>>(
        CTX, Wout, out_proj_b, FE, NSPAN, H_, H_, INDIM_);
    feats_fill_kernel<<<NSPAN, 256, 0, stream>>>(span_widths, width_table, cls_reps, FE);

    // H1 = relu(FEATS @ w1^T + b1)  -> bf16 (16384 x 3072)
    gemm_bf16_kernel<true,true><<<dim3(INNER_/128, NSPAN/128), 256, 0, stream>>>(
        FE, W1b, b1, H1, NSPAN, INNER_, INDIM_, INNER_);

    // out = H1 @ w2^T + b2  -> f32 d_out (16384 x 768)
    gemm_bf16_kernel<false,false><<<dim3(768/128, NSPAN/128), 256, 0, stream>>>(
        H1, W2b, b2, (float*)d_out, NSPAN, H_, INNER_, H_);
}

// Round 2
// 325.388 us; speedup vs baseline: 1.7089x; 1.7089x over previous
//
#include <hip/hip_runtime.h>
#include <hip/hip_bf16.h>
#include <math.h>

// Problem constants
#define B_      4
#define S_      512
#define H_      768
#define NH_     4
#define DH_     192
#define N_      4096          // spans per batch
#define WD_     64
#define INNER_  3072
#define INDIM_  1600
#define SP1     513           // S+1 (CLS prepended)
#define ROWS_X  (B_*SP1)      // 2052
#define ROWS_XP 2176          // padded to multiple of 128 (17*128)
#define NSPAN   (B_*N_)       // 16384

typedef __attribute__((ext_vector_type(8))) short bf16x8;
typedef __attribute__((ext_vector_type(4))) float f32x4;

__device__ __forceinline__ unsigned short f2bf(float f){
    unsigned u = __builtin_bit_cast(unsigned, f);
    u = u + 0x7FFFu + ((u >> 16) & 1u);   // round-to-nearest-even
    return (unsigned short)(u >> 16);
}

__device__ __forceinline__ float wave_sum(float p){
    #pragma unroll
    for (int off = 32; off > 0; off >>= 1) p += __shfl_down(p, off);
    return p;
}

// async global->LDS, 16B per lane. lds must be wave-uniform; g is per-lane.
__device__ __forceinline__ void gld16(unsigned short* lds, const unsigned short* g){
    __builtin_amdgcn_global_load_lds(
        (const __attribute__((address_space(1))) unsigned int*)(const void*)g,
        (__attribute__((address_space(3))) unsigned int*)(void*)lds,
        16, 0, 0);
}

// ---------------------------------------------------------------------------
// 0. span_masks encoding detection: flag=0 -> 4-byte elems, flag=1 -> 1-byte.
// ---------------------------------------------------------------------------
__global__ void detect_mask_kernel(const unsigned* __restrict__ masks, int* __restrict__ flag){
    __shared__ int s_any;
    if (threadIdx.x == 0) s_any = 0;
    __syncthreads();
    int any = 0;
    for (int i = threadIdx.x; i < 4096; i += 256){
        unsigned v = masks[i];
        if (!(v == 0u || v == 1u || v == 0x3F800000u)) any = 1;
    }
    if (any) s_any = 1;
    __syncthreads();
    if (threadIdx.x == 0) *flag = s_any;
}

// ---------------------------------------------------------------------------
// 1. f32 -> bf16 conversion (grid-stride over float4)
// ---------------------------------------------------------------------------
__global__ void conv_f32_bf16(const float* __restrict__ in, unsigned short* __restrict__ out, long n4){
    long i = (long)blockIdx.x * blockDim.x + threadIdx.x;
    long stride = (long)gridDim.x * blockDim.x;
    for (; i < n4; i += stride){
        float4 v = ((const float4*)in)[i];
        ushort4 o;
        o.x = f2bf(v.x); o.y = f2bf(v.y); o.z = f2bf(v.z); o.w = f2bf(v.w);
        ((ushort4*)out)[i] = o;
    }
}

// w1 cols [0,768) -> compact bf16 (3072 x 768)
__global__ void conv_w1a_kernel(const float* __restrict__ w1, unsigned short* __restrict__ out){
    int i = blockIdx.x;
    int k4 = threadIdx.x;                 // 0..191
    if (k4 < 192){
        float4 v = ((const float4*)&w1[(long)i * INDIM_])[k4];
        ushort4 o; o.x = f2bf(v.x); o.y = f2bf(v.y); o.z = f2bf(v.z); o.w = f2bf(v.w);
        ((ushort4*)&out[(long)i * 768])[k4] = o;
    }
}

// OutT[k][j] = bf16(out_proj_w[j][k])  (768x768 transpose-convert)
__global__ void transconv_kernel(const float* __restrict__ in, unsigned short* __restrict__ out){
    __shared__ float tile[32][33];
    int bx = blockIdx.x * 32, by = blockIdx.y * 32;
    int tx = threadIdx.x & 31, ty = threadIdx.x >> 5;   // 32x8
    #pragma unroll
    for (int r = 0; r < 32; r += 8)
        tile[ty + r][tx] = in[(long)(by + ty + r) * 768 + bx + tx];
    __syncthreads();
    #pragma unroll
    for (int r = 0; r < 32; r += 8)
        out[(long)(bx + ty + r) * 768 + by + tx] = f2bf(tile[tx][ty + r]);
}

// ---------------------------------------------------------------------------
// 2. X = [cls_embedding; token_reps] per batch, bf16. rows 0..2051 (tail garbage ok)
// ---------------------------------------------------------------------------
__global__ void build_x_kernel(const float* __restrict__ tok, const float* __restrict__ clsemb,
                               unsigned short* __restrict__ X){
    int r = blockIdx.x;
    int b = r / SP1, s = r % SP1;
    const float* src = (s == 0) ? clsemb : &tok[((long)b * S_ + (s - 1)) * H_];
    for (int d = threadIdx.x; d < H_; d += 256)
        X[(long)r * H_ + d] = f2bf(src[d]);
}

// ---------------------------------------------------------------------------
// 3. q = cls_embedding @ wq.T + bq   (wave-per-output, coalesced)
// ---------------------------------------------------------------------------
__global__ void q_kernel(const float* __restrict__ clsemb, const float* __restrict__ w,
                         const float* __restrict__ bias, float* __restrict__ q){
    int j = blockIdx.x * 4 + (threadIdx.x >> 6);
    int lane = threadIdx.x & 63;
    const float* wr = &w[(long)j * H_];
    float p = 0.f;
    #pragma unroll
    for (int i = 0; i < 12; ++i) p += clsemb[lane + 64*i] * wr[lane + 64*i];
    p = wave_sum(p);
    if (lane == 0) q[j] = p + bias[j];
}

// ---------------------------------------------------------------------------
// 4. BiasC[b][i] = b1[i] + dot(out_proj_b, w1[i][0:768]) + dot(cls_reps[b], w1[i][832:1600])
// ---------------------------------------------------------------------------
__global__ void biasc_kernel(const float* __restrict__ w1, const float* __restrict__ b1,
                             const float* __restrict__ opb, const float* __restrict__ cls_reps,
                             float* __restrict__ BiasC){
    int i = blockIdx.x * 4 + (threadIdx.x >> 6);
    int lane = threadIdx.x & 63;
    const float* row = &w1[(long)i * INDIM_];
    float p0 = 0.f, pb0 = 0.f, pb1 = 0.f, pb2 = 0.f, pb3 = 0.f;
    #pragma unroll
    for (int t = 0; t < 12; ++t){
        int k = lane + 64*t;
        p0 += opb[k] * row[k];
        float rv = row[832 + k];
        pb0 += cls_reps[0*H_ + k] * rv;
        pb1 += cls_reps[1*H_ + k] * rv;
        pb2 += cls_reps[2*H_ + k] * rv;
        pb3 += cls_reps[3*H_ + k] * rv;
    }
    p0 = wave_sum(p0); pb0 = wave_sum(pb0); pb1 = wave_sum(pb1);
    pb2 = wave_sum(pb2); pb3 = wave_sum(pb3);
    if (lane == 0){
        float base = b1[i] + p0;
        BiasC[0*INNER_ + i] = base + pb0;
        BiasC[1*INNER_ + i] = base + pb1;
        BiasC[2*INNER_ + i] = base + pb2;
        BiasC[3*INNER_ + i] = base + pb3;
    }
}

// WC[w][i] = dot(width_table[w], w1[i][768:832])
__global__ void wc_kernel(const float* __restrict__ w1, const float* __restrict__ wtab,
                          float* __restrict__ WC){
    int i = blockIdx.x * 4 + (threadIdx.x >> 6);
    int lane = threadIdx.x & 63;
    float rv = w1[(long)i * INDIM_ + 768 + lane];
    #pragma unroll
    for (int w = 0; w < 9; ++w){
        float p = wave_sum(wtab[w * WD_ + lane] * rv);
        if (lane == 0) WC[w * INNER_ + i] = p;
    }
}

// ---------------------------------------------------------------------------
// 5. base_scores[b][h][s] = (q[h,:] . k[b,s,h,:]) * scale
// ---------------------------------------------------------------------------
__global__ void scores_kernel(const float* __restrict__ q, const float* __restrict__ KV,
                              float* __restrict__ SC){
    int r = blockIdx.x;                       // b*513 + s
    int h = threadIdx.x >> 6, lane = threadIdx.x & 63;
    const float* krow = &KV[(long)r * 1536 + h * DH_];
    const float* qh   = &q[h * DH_];
    float p = 0.f;
    #pragma unroll
    for (int i = 0; i < 3; ++i) p += qh[lane + 64*i] * krow[lane + 64*i];
    p = wave_sum(p);
    if (lane == 0){
        const float scale = 0.0721687836487032f;   // 1/sqrt(192)
        SC[((r / SP1) * NH_ + h) * SP1 + (r % SP1)] = p * scale;
    }
}

// ---------------------------------------------------------------------------
// 6. Per-span attention: softmax over {CLS} U [start,end), ctx -> bf16 CTX
// ---------------------------------------------------------------------------
__global__ __launch_bounds__(256) void attn_kernel(
    const int* __restrict__ span_ids, const void* __restrict__ masks,
    const int* __restrict__ flag, const float* __restrict__ SC,
    const float* __restrict__ KV, unsigned short* __restrict__ CTX)
{
    int blk = blockIdx.x;
    int b = blk >> 12, n = blk & (N_ - 1);
    int t = threadIdx.x;
    __shared__ float w_sh[NH_][9];
    __shared__ int info[2];

    if (t == 0){
        long idx = (long)b * N_ + n;
        int start = span_ids[idx * 2 + 0];
        int end   = span_ids[idx * 2 + 1];
        bool sm = (*flag == 0) ? (((const unsigned*)masks)[idx] != 0u)
                               : (((const unsigned char*)masks)[idx] != 0);
        int cnt = sm ? (end - start) : 0;
        if (cnt < 0) cnt = 0;
        if (cnt > 8) cnt = 8;
        if (start < 0) start = 0;
        if (start + cnt > S_) cnt = S_ - start;
        info[0] = start; info[1] = cnt;
    }
    __syncthreads();
    int start = info[0], cnt = info[1];

    if (t < NH_){
        int h = t;
        const float* sc = &SC[((long)b * NH_ + h) * SP1];
        float m = sc[0];
        for (int j = 0; j < cnt; ++j) m = fmaxf(m, sc[1 + start + j]);
        float e0 = expf(sc[0] - m), sum = e0;
        float ej[8];
        for (int j = 0; j < cnt; ++j){ ej[j] = expf(sc[1 + start + j] - m); sum += ej[j]; }
        float inv = 1.f / sum;
        w_sh[h][0] = e0 * inv;
        for (int j = 0; j < cnt; ++j) w_sh[h][1 + j] = ej[j] * inv;
    }
    __syncthreads();

    long ctxbase = ((long)b * N_ + n) * H_;
    const float* V = &KV[(long)(b * SP1) * 1536 + H_];
    #pragma unroll
    for (int i = 0; i < 3; ++i){
        int d = t + 256 * i;
        int h = d / DH_;
        float a = w_sh[h][0] * V[d];
        for (int j = 0; j < cnt; ++j)
            a += w_sh[h][1 + j] * V[(long)(1 + start + j) * 1536 + d];
        CTX[ctxbase + d] = f2bf(a);
    }
}

// ---------------------------------------------------------------------------
// 7. m97-structure bf16 MFMA GEMM: C(MxN) = A(MxK) @ B(NxK)^T.
//    128x128 tile, BK=32, global_load_lds w16, linear LDS, 2-barrier loop.
//    REQUIRES: M%128==0, N%128==0, K%32==0 (pad buffers).
//    EPI: 0 = f32 out + optional col bias
//         1 = bf16 out + optional col bias
//         2 = bf16 out + relu + BiasC[4][N] (batch) + WC[9][N] (width) row bias
// ---------------------------------------------------------------------------
template<int EPI>
__global__ __launch_bounds__(256, 2) void gemm97(
    const unsigned short* __restrict__ A, const unsigned short* __restrict__ Bm,
    const float* __restrict__ biasA, const float* __restrict__ biasB,
    const int* __restrict__ widths, void* __restrict__ Cp,
    int M, int N, int K, int lda, int ldb, int ldc, int nbx)
{
    __shared__ unsigned short As[128 * 32];
    __shared__ unsigned short Bs[128 * 32];
    const int t = threadIdx.x, lane = t & 63, wave = t >> 6;
    const int wr = wave >> 1, wcid = wave & 1;

    // XCD-aware swizzle (identity when grid not divisible by 8)
    int nwg = gridDim.x;
    int bid = blockIdx.x;
    int swz = ((nwg & 7) == 0) ? ((bid & 7) * (nwg >> 3) + (bid >> 3)) : bid;
    const int m0 = (swz / nbx) * 128;
    const int n0 = (swz % nbx) * 128;

    f32x4 acc[4][4];
    #pragma unroll
    for (int i = 0; i < 4; ++i)
        #pragma unroll
        for (int j = 0; j < 4; ++j)
            acc[i][j] = (f32x4){0.f, 0.f, 0.f, 0.f};

    // staging addresses: wave w stages 32 rows of A and B per K-step,
    // 2 x global_load_lds each (16 rows / 1024B per instruction)
    const unsigned short* gA = A + (long)(m0 + wave*32 + (lane >> 2)) * lda + (lane & 3) * 8;
    const unsigned short* gB = Bm + (long)(n0 + wave*32 + (lane >> 2)) * ldb + (lane & 3) * 8;
    unsigned short* lA = &As[wave * 32 * 32];
    unsigned short* lB = &Bs[wave * 32 * 32];
    const long a16 = (long)16 * lda, b16 = (long)16 * ldb;

    for (int k0 = 0; k0 < K; k0 += 32){
        gld16(lA,       gA + k0);
        gld16(lA + 512, gA + a16 + k0);
        gld16(lB,       gB + k0);
        gld16(lB + 512, gB + b16 + k0);
        __syncthreads();        // vmcnt(0) drain + barrier: staged tile visible

        bf16x8 af[4], bfr[4];
        #pragma unroll
        for (int f = 0; f < 4; ++f){
            af[f]  = *(const bf16x8*)&As[(wr*64 + f*16 + (lane & 15)) * 32 + (lane >> 4) * 8];
            bfr[f] = *(const bf16x8*)&Bs[(wcid*64 + f*16 + (lane & 15)) * 32 + (lane >> 4) * 8];
        }
        #pragma unroll
        for (int i = 0; i < 4; ++i)
            #pragma unroll
            for (int j = 0; j < 4; ++j)
                acc[i][j] = __builtin_amdgcn_mfma_f32_16x16x32_bf16(af[i], bfr[j], acc[i][j], 0, 0, 0);
        __syncthreads();        // reads done before next stage overwrites
    }

    const int r0 = (lane >> 4) * 4;
    const int cc = lane & 15;
    const float* bc = (EPI == 2) ? (biasA + (m0 >> 12) * (long)N) : nullptr;
    #pragma unroll
    for (int i = 0; i < 4; ++i){
        int rowb = m0 + wr*64 + i*16 + r0;
        int wdx[4];
        if (EPI == 2){
            #pragma unroll
            for (int r = 0; r < 4; ++r){
                int wv = widths[rowb + r];
                wdx[r] = (wv < 0) ? 0 : ((wv > 8) ? 8 : wv);
            }
        }
        #pragma unroll
        for (int j = 0; j < 4; ++j){
            int col = n0 + wcid*64 + j*16 + cc;
            float cb = 0.f;
            if (EPI != 2 && biasA) cb = biasA[col];
            #pragma unroll
            for (int r = 0; r < 4; ++r){
                long o = (long)(rowb + r) * ldc + col;
                float v = acc[i][j][r] + cb;
                if (EPI == 2){
                    v += bc[col] + biasB[(long)wdx[r] * N + col];
                    v = fmaxf(v, 0.f);
                    ((unsigned short*)Cp)[o] = f2bf(v);
                } else if (EPI == 1){
                    ((unsigned short*)Cp)[o] = f2bf(v);
                } else {
                    ((float*)Cp)[o] = v;
                }
            }
        }
    }
}

// ---------------------------------------------------------------------------
extern "C" void kernel_launch(void* const* d_in, const int* in_sizes, int n_in,
                              void* d_out, int out_size, void* d_ws, size_t ws_size,
                              hipStream_t stream)
{
    const float* token_reps  = (const float*)d_in[0];
    const int*   span_ids    = (const int*)d_in[1];
    const void*  span_masks  = d_in[2];
    const float* cls_reps    = (const float*)d_in[3];
    const int*   span_widths = (const int*)d_in[4];
    const float* cls_emb     = (const float*)d_in[5];
    const float* in_proj_w   = (const float*)d_in[6];
    const float* in_proj_b   = (const float*)d_in[7];
    const float* out_proj_w  = (const float*)d_in[8];
    const float* out_proj_b  = (const float*)d_in[9];
    const float* width_table = (const float*)d_in[10];
    const float* w1          = (const float*)d_in[11];
    const float* b1          = (const float*)d_in[12];
    const float* w2          = (const float*)d_in[13];
    const float* b2          = (const float*)d_in[14];

    char* ws = (char*)d_ws;
    size_t off = 0;
    auto alloc = [&](size_t bytes)->char*{
        char* p = ws + off;
        off += (bytes + 255) & ~(size_t)255;
        return p;
    };
    int*            flag  = (int*)           alloc(4);
    float*          qbuf  = (float*)         alloc((size_t)H_ * 4);
    unsigned short* Xb    = (unsigned short*)alloc((size_t)ROWS_XP * H_ * 2);
    unsigned short* Wkv   = (unsigned short*)alloc((size_t)1536 * H_ * 2);
    float*          KV    = (float*)         alloc((size_t)ROWS_XP * 1536 * 4);
    float*          SC    = (float*)         alloc((size_t)B_ * NH_ * SP1 * 4);
    unsigned short* CTX   = (unsigned short*)alloc((size_t)NSPAN * H_ * 2);
    unsigned short* W1a   = (unsigned short*)alloc((size_t)INNER_ * H_ * 2);
    unsigned short* OutT  = (unsigned short*)alloc((size_t)H_ * H_ * 2);
    unsigned short* Wfuse = (unsigned short*)alloc((size_t)INNER_ * H_ * 2);
    unsigned short* W2b   = (unsigned short*)alloc((size_t)H_ * INNER_ * 2);
    unsigned short* H1    = (unsigned short*)alloc((size_t)NSPAN * INNER_ * 2);
    float*          BiasC = (float*)         alloc((size_t)B_ * INNER_ * 4);
    float*          WC    = (float*)         alloc((size_t)9 * INNER_ * 4);
    (void)ws_size; (void)in_sizes; (void)n_in; (void)out_size;

    // prep / conversions
    detect_mask_kernel<<<1, 256, 0, stream>>>((const unsigned*)span_masks, flag);
    build_x_kernel<<<ROWS_X, 256, 0, stream>>>(token_reps, cls_emb, Xb);
    conv_f32_bf16<<<512, 256, 0, stream>>>(in_proj_w + (size_t)768 * H_, Wkv, (long)(1536 * H_ / 4));
    conv_f32_bf16<<<512, 256, 0, stream>>>(w2, W2b, (long)(H_ * INNER_ / 4));
    conv_w1a_kernel<<<INNER_, 192, 0, stream>>>(w1, W1a);
    transconv_kernel<<<dim3(24, 24), 256, 0, stream>>>(out_proj_w, OutT);
    q_kernel<<<H_ / 4, 256, 0, stream>>>(cls_emb, in_proj_w, in_proj_b, qbuf);
    biasc_kernel<<<INNER_ / 4, 256, 0, stream>>>(w1, b1, out_proj_b, cls_reps, BiasC);
    wc_kernel<<<INNER_ / 4, 256, 0, stream>>>(w1, width_table, WC);

    // Wfused[i][k] = sum_j w1a[i][j] * out_proj_w[j][k]   (3072x768, K=768)
    gemm97<1><<<(768/128) * (INNER_/128), 256, 0, stream>>>(
        W1a, OutT, nullptr, nullptr, nullptr, Wfuse,
        INNER_, 768, 768, 768, 768, 768, 768/128);

    // KV = X @ [wk;wv]^T + b   (2176x1536, K=768; tail rows garbage, never read)
    gemm97<0><<<(1536/128) * (ROWS_XP/128), 256, 0, stream>>>(
        Xb, Wkv, in_proj_b + 768, nullptr, nullptr, KV,
        ROWS_XP, 1536, 768, 768, 768, 1536, 1536/128);

    scores_kernel<<<ROWS_X, 256, 0, stream>>>(qbuf, KV, SC);
    attn_kernel<<<NSPAN, 256, 0, stream>>>(span_ids, span_masks, flag, SC, KV, CTX);

    // H1 = relu(CTX @ Wfused^T + BiasC[b] + WC[width])   (16384x3072, K=768)
    gemm97<2><<<(INNER_/128) * (NSPAN/128), 256, 0, stream>>>(
        CTX, Wfuse, BiasC, WC, span_widths, H1,
        NSPAN, INNER_, 768, 768, 768, INNER_, INNER_/128);

    // out = H1 @ w2^T + b2   (16384x768, K=3072) -> f32 d_out
    gemm97<0><<<(768/128) * (NSPAN/128), 256, 0, stream>>>(
        H1, W2b, b2, nullptr, nullptr, (float*)d_out,
        NSPAN, 768, 3072, 3072, 3072, 768, 768/128);
}

// Round 3
// 301.012 us; speedup vs baseline: 1.8473x; 1.0810x over previous
//
#include <hip/hip_runtime.h>
#include <hip/hip_bf16.h>
#include <math.h>

// Problem constants
#define B_      4
#define S_      512
#define H_      768
#define NH_     4
#define DH_     192
#define N_      4096          // spans per batch
#define WD_     64
#define INNER_  3072
#define INDIM_  1600
#define SP1     513           // S+1 (CLS prepended)
#define ROWS_X  (B_*SP1)      // 2052
#define ROWS_XP 2176          // padded to multiple of 128
#define NSPAN   (B_*N_)       // 16384

typedef __attribute__((ext_vector_type(8))) short bf16x8;
typedef __attribute__((ext_vector_type(4))) float f32x4;

__device__ __forceinline__ unsigned short f2bf(float f){
    unsigned u = __builtin_bit_cast(unsigned, f);
    u = u + 0x7FFFu + ((u >> 16) & 1u);   // round-to-nearest-even
    return (unsigned short)(u >> 16);
}

__device__ __forceinline__ float wave_sum(float p){
    #pragma unroll
    for (int off = 32; off > 0; off >>= 1) p += __shfl_down(p, off);
    return p;
}

// async global->LDS, 16B per lane. lds must be wave-uniform; g is per-lane.
__device__ __forceinline__ void gld16(unsigned short* lds, const unsigned short* g){
    __builtin_amdgcn_global_load_lds(
        (const __attribute__((address_space(1))) unsigned int*)(const void*)g,
        (__attribute__((address_space(3))) unsigned int*)(void*)lds,
        16, 0, 0);
}

__device__ __forceinline__ void wgbar(){
    asm volatile("" ::: "memory");
    __builtin_amdgcn_s_barrier();
    asm volatile("" ::: "memory");
}
#define VMW(n) asm volatile("s_waitcnt vmcnt(" #n ")" ::: "memory")

// ---------------------------------------------------------------------------
// 0. span_masks encoding detection
// ---------------------------------------------------------------------------
__global__ void detect_mask_kernel(const unsigned* __restrict__ masks, int* __restrict__ flag){
    __shared__ int s_any;
    if (threadIdx.x == 0) s_any = 0;
    __syncthreads();
    int any = 0;
    for (int i = threadIdx.x; i < 4096; i += 256){
        unsigned v = masks[i];
        if (!(v == 0u || v == 1u || v == 0x3F800000u)) any = 1;
    }
    if (any) s_any = 1;
    __syncthreads();
    if (threadIdx.x == 0) *flag = s_any;
}

// ---------------------------------------------------------------------------
// 1. f32 -> bf16 conversions
// ---------------------------------------------------------------------------
__global__ void conv_f32_bf16(const float* __restrict__ in, unsigned short* __restrict__ out, long n4){
    long i = (long)blockIdx.x * blockDim.x + threadIdx.x;
    long stride = (long)gridDim.x * blockDim.x;
    for (; i < n4; i += stride){
        float4 v = ((const float4*)in)[i];
        ushort4 o;
        o.x = f2bf(v.x); o.y = f2bf(v.y); o.z = f2bf(v.z); o.w = f2bf(v.w);
        ((ushort4*)out)[i] = o;
    }
}

__global__ void conv_w1a_kernel(const float* __restrict__ w1, unsigned short* __restrict__ out){
    int i = blockIdx.x;
    int k4 = threadIdx.x;
    if (k4 < 192){
        float4 v = ((const float4*)&w1[(long)i * INDIM_])[k4];
        ushort4 o; o.x = f2bf(v.x); o.y = f2bf(v.y); o.z = f2bf(v.z); o.w = f2bf(v.w);
        ((ushort4*)&out[(long)i * 768])[k4] = o;
    }
}

__global__ void transconv_kernel(const float* __restrict__ in, unsigned short* __restrict__ out){
    __shared__ float tile[32][33];
    int bx = blockIdx.x * 32, by = blockIdx.y * 32;
    int tx = threadIdx.x & 31, ty = threadIdx.x >> 5;
    #pragma unroll
    for (int r = 0; r < 32; r += 8)
        tile[ty + r][tx] = in[(long)(by + ty + r) * 768 + bx + tx];
    __syncthreads();
    #pragma unroll
    for (int r = 0; r < 32; r += 8)
        out[(long)(bx + ty + r) * 768 + by + tx] = f2bf(tile[tx][ty + r]);
}

// ---------------------------------------------------------------------------
// 2. X = [cls_embedding; token_reps], bf16
// ---------------------------------------------------------------------------
__global__ void build_x_kernel(const float* __restrict__ tok, const float* __restrict__ clsemb,
                               unsigned short* __restrict__ X){
    int r = blockIdx.x;
    int b = r / SP1, s = r % SP1;
    const float* src = (s == 0) ? clsemb : &tok[((long)b * S_ + (s - 1)) * H_];
    for (int d = threadIdx.x; d < H_; d += 256)
        X[(long)r * H_ + d] = f2bf(src[d]);
}

// ---------------------------------------------------------------------------
// 3. q projection
// ---------------------------------------------------------------------------
__global__ void q_kernel(const float* __restrict__ clsemb, const float* __restrict__ w,
                         const float* __restrict__ bias, float* __restrict__ q){
    int j = blockIdx.x * 4 + (threadIdx.x >> 6);
    int lane = threadIdx.x & 63;
    const float* wr = &w[(long)j * H_];
    float p = 0.f;
    #pragma unroll
    for (int i = 0; i < 12; ++i) p += clsemb[lane + 64*i] * wr[lane + 64*i];
    p = wave_sum(p);
    if (lane == 0) q[j] = p + bias[j];
}

// ---------------------------------------------------------------------------
// 4. BiasC / WC precomputes
// ---------------------------------------------------------------------------
__global__ void biasc_kernel(const float* __restrict__ w1, const float* __restrict__ b1,
                             const float* __restrict__ opb, const float* __restrict__ cls_reps,
                             float* __restrict__ BiasC){
    int i = blockIdx.x * 4 + (threadIdx.x >> 6);
    int lane = threadIdx.x & 63;
    const float* row = &w1[(long)i * INDIM_];
    float p0 = 0.f, pb0 = 0.f, pb1 = 0.f, pb2 = 0.f, pb3 = 0.f;
    #pragma unroll
    for (int t = 0; t < 12; ++t){
        int k = lane + 64*t;
        p0 += opb[k] * row[k];
        float rv = row[832 + k];
        pb0 += cls_reps[0*H_ + k] * rv;
        pb1 += cls_reps[1*H_ + k] * rv;
        pb2 += cls_reps[2*H_ + k] * rv;
        pb3 += cls_reps[3*H_ + k] * rv;
    }
    p0 = wave_sum(p0); pb0 = wave_sum(pb0); pb1 = wave_sum(pb1);
    pb2 = wave_sum(pb2); pb3 = wave_sum(pb3);
    if (lane == 0){
        float base = b1[i] + p0;
        BiasC[0*INNER_ + i] = base + pb0;
        BiasC[1*INNER_ + i] = base + pb1;
        BiasC[2*INNER_ + i] = base + pb2;
        BiasC[3*INNER_ + i] = base + pb3;
    }
}

__global__ void wc_kernel(const float* __restrict__ w1, const float* __restrict__ wtab,
                          float* __restrict__ WC){
    int i = blockIdx.x * 4 + (threadIdx.x >> 6);
    int lane = threadIdx.x & 63;
    float rv = w1[(long)i * INDIM_ + 768 + lane];
    #pragma unroll
    for (int w = 0; w < 9; ++w){
        float p = wave_sum(wtab[w * WD_ + lane] * rv);
        if (lane == 0) WC[w * INNER_ + i] = p;
    }
}

// ---------------------------------------------------------------------------
// 5. base scores
// ---------------------------------------------------------------------------
__global__ void scores_kernel(const float* __restrict__ q, const float* __restrict__ KV,
                              float* __restrict__ SC){
    int r = blockIdx.x;
    int h = threadIdx.x >> 6, lane = threadIdx.x & 63;
    const float* krow = &KV[(long)r * 1536 + h * DH_];
    const float* qh   = &q[h * DH_];
    float p = 0.f;
    #pragma unroll
    for (int i = 0; i < 3; ++i) p += qh[lane + 64*i] * krow[lane + 64*i];
    p = wave_sum(p);
    if (lane == 0){
        const float scale = 0.0721687836487032f;
        SC[((r / SP1) * NH_ + h) * SP1 + (r % SP1)] = p * scale;
    }
}

// ---------------------------------------------------------------------------
// 6. per-span attention -> CTX bf16
// ---------------------------------------------------------------------------
__global__ __launch_bounds__(256) void attn_kernel(
    const int* __restrict__ span_ids, const void* __restrict__ masks,
    const int* __restrict__ flag, const float* __restrict__ SC,
    const float* __restrict__ KV, unsigned short* __restrict__ CTX)
{
    int blk = blockIdx.x;
    int b = blk >> 12, n = blk & (N_ - 1);
    int t = threadIdx.x;
    __shared__ float w_sh[NH_][9];
    __shared__ int info[2];

    if (t == 0){
        long idx = (long)b * N_ + n;
        int start = span_ids[idx * 2 + 0];
        int end   = span_ids[idx * 2 + 1];
        bool sm = (*flag == 0) ? (((const unsigned*)masks)[idx] != 0u)
                               : (((const unsigned char*)masks)[idx] != 0);
        int cnt = sm ? (end - start) : 0;
        if (cnt < 0) cnt = 0;
        if (cnt > 8) cnt = 8;
        if (start < 0) start = 0;
        if (start + cnt > S_) cnt = S_ - start;
        info[0] = start; info[1] = cnt;
    }
    __syncthreads();
    int start = info[0], cnt = info[1];

    if (t < NH_){
        int h = t;
        const float* sc = &SC[((long)b * NH_ + h) * SP1];
        float m = sc[0];
        for (int j = 0; j < cnt; ++j) m = fmaxf(m, sc[1 + start + j]);
        float e0 = expf(sc[0] - m), sum = e0;
        float ej[8];
        for (int j = 0; j < cnt; ++j){ ej[j] = expf(sc[1 + start + j] - m); sum += ej[j]; }
        float inv = 1.f / sum;
        w_sh[h][0] = e0 * inv;
        for (int j = 0; j < cnt; ++j) w_sh[h][1 + j] = ej[j] * inv;
    }
    __syncthreads();

    long ctxbase = ((long)b * N_ + n) * H_;
    const float* V = &KV[(long)(b * SP1) * 1536 + H_];
    #pragma unroll
    for (int i = 0; i < 3; ++i){
        int d = t + 256 * i;
        int h = d / DH_;
        float a = w_sh[h][0] * V[d];
        for (int j = 0; j < cnt; ++j)
            a += w_sh[h][1 + j] * V[(long)(1 + start + j) * 1536 + d];
        CTX[ctxbase + d] = f2bf(a);
    }
}

// ---------------------------------------------------------------------------
// 7a. m97 128x128 GEMM (proven) — kept for the small GEMMs (KV, Wfuse)
// ---------------------------------------------------------------------------
template<int EPI>
__global__ __launch_bounds__(256, 2) void gemm97(
    const unsigned short* __restrict__ A, const unsigned short* __restrict__ Bm,
    const float* __restrict__ biasA, void* __restrict__ Cp,
    int M, int N, int K, int lda, int ldb, int ldc, int nbx)
{
    __shared__ unsigned short As[128 * 32];
    __shared__ unsigned short Bs[128 * 32];
    const int t = threadIdx.x, lane = t & 63, wave = t >> 6;
    const int wr = wave >> 1, wcid = wave & 1;

    int nwg = gridDim.x;
    int bid = blockIdx.x;
    int swz = ((nwg & 7) == 0) ? ((bid & 7) * (nwg >> 3) + (bid >> 3)) : bid;
    const int m0 = (swz / nbx) * 128;
    const int n0 = (swz % nbx) * 128;

    f32x4 acc[4][4];
    #pragma unroll
    for (int i = 0; i < 4; ++i)
        #pragma unroll
        for (int j = 0; j < 4; ++j)
            acc[i][j] = (f32x4){0.f, 0.f, 0.f, 0.f};

    const unsigned short* gA = A + (long)(m0 + wave*32 + (lane >> 2)) * lda + (lane & 3) * 8;
    const unsigned short* gB = Bm + (long)(n0 + wave*32 + (lane >> 2)) * ldb + (lane & 3) * 8;
    unsigned short* lA = &As[wave * 32 * 32];
    unsigned short* lB = &Bs[wave * 32 * 32];
    const long a16 = (long)16 * lda, b16 = (long)16 * ldb;

    for (int k0 = 0; k0 < K; k0 += 32){
        gld16(lA,       gA + k0);
        gld16(lA + 512, gA + a16 + k0);
        gld16(lB,       gB + k0);
        gld16(lB + 512, gB + b16 + k0);
        __syncthreads();

        bf16x8 af[4], bfr[4];
        #pragma unroll
        for (int f = 0; f < 4; ++f){
            af[f]  = *(const bf16x8*)&As[(wr*64 + f*16 + (lane & 15)) * 32 + (lane >> 4) * 8];
            bfr[f] = *(const bf16x8*)&Bs[(wcid*64 + f*16 + (lane & 15)) * 32 + (lane >> 4) * 8];
        }
        #pragma unroll
        for (int i = 0; i < 4; ++i)
            #pragma unroll
            for (int j = 0; j < 4; ++j)
                acc[i][j] = __builtin_amdgcn_mfma_f32_16x16x32_bf16(af[i], bfr[j], acc[i][j], 0, 0, 0);
        __syncthreads();
    }

    const int r0 = (lane >> 4) * 4;
    const int cc = lane & 15;
    #pragma unroll
    for (int i = 0; i < 4; ++i){
        int rowb = m0 + wr*64 + i*16 + r0;
        #pragma unroll
        for (int j = 0; j < 4; ++j){
            int col = n0 + wcid*64 + j*16 + cc;
            float cb = biasA ? biasA[col] : 0.f;
            #pragma unroll
            for (int r = 0; r < 4; ++r){
                long o = (long)(rowb + r) * ldc + col;
                float v = acc[i][j][r] + cb;
                if (EPI == 1) ((unsigned short*)Cp)[o] = f2bf(v);
                else          ((float*)Cp)[o] = v;
            }
        }
    }
}

// ---------------------------------------------------------------------------
// 7b. 256x256 8-phase GEMM (T2 swizzle + T3/T4 counted vmcnt + T5 setprio)
//     C(MxN) = A(MxK) @ B(NxK)^T.  M%256==0, N%256==0, K%64==0, K>=128.
//     8 waves (2M x 4N), per-wave 128x64 output, BK=64, LDS 128KB dbuf.
//     LDS row permutation groups each phase's staging unit contiguously:
//       A: rho = mq*128 + wr*64 + (r&63)   (q0,q2 | q1,q3)
//       B: rho = (r>>5 & 1)*128 + (r>>6)*32 + (r&31)  (even | odd octants)
//     Col XOR-swizzle (byte): c ^ ((rho&7)<<4), pre-applied on global source.
//     Waits: vmcnt(4) at end of ph1, ph2, ph4 (epilogue 4->2->0). Never 0 in loop.
//     EPI: 0 = f32 out + col bias; 2 = bf16 out + relu + BiasC[4][N] + WC[9][N]
// ---------------------------------------------------------------------------
template<int EPI, int LDA_, int LDB_>
__global__ __launch_bounds__(512, 2) void gemm256(
    const unsigned short* __restrict__ A, const unsigned short* __restrict__ Bm,
    const float* __restrict__ biasA, const float* __restrict__ biasB,
    const int* __restrict__ widths, void* __restrict__ Cp,
    int K, int ldc, int nbx)
{
    __shared__ __align__(16) unsigned char lds[131072];
    const int t = threadIdx.x, lane = t & 63;
    const int wave = t >> 6;
    const int wr = wave >> 2, wc = wave & 3;      // 2M x 4N waves

    int nwg = gridDim.x, bid = blockIdx.x;
    int swz = ((nwg & 7) == 0) ? ((bid & 7) * (nwg >> 3) + (bid >> 3)) : bid;
    const int m0 = (swz / nbx) * 256;
    const int n0 = (swz % nbx) * 256;

    // ---- staging precompute (per-thread) ----
    const int rQ = t >> 3;                                  // 0..63
    const int cswz = ((t & 7) ^ (rQ & 7)) << 3;             // elements (16B granules)
    const unsigned short* sA = A + (long)(m0 + rQ) * LDA_ + cswz;
    const unsigned short* sB = Bm + (long)(n0 + ((rQ >> 5) * 64 + (rQ & 31))) * LDB_ + cswz;
    const int wsl = wave * 1024;                            // per-wave LDS slice (bytes)

    // ---- ds_read precompute ----
    const int aRow = (wr * 64 + (lane & 15)) * 128;         // bytes
    const int bRow = (wc * 32 + (lane & 15)) * 128;
    const int pcl0 = (((lane >> 4) * 16)) ^ ((lane & 7) << 4);
    const int pcl1 = (64 + ((lane >> 4) * 16)) ^ ((lane & 7) << 4);

    f32x4 acc[8][4];
    #pragma unroll
    for (int i = 0; i < 8; ++i)
        #pragma unroll
        for (int j = 0; j < 4; ++j)
            acc[i][j] = (f32x4){0.f, 0.f, 0.f, 0.f};

    const int KT = K >> 6;

#define STG_(off, src) gld16((unsigned short*)(void*)(lds + (off) + wsl), (src))

    // ---- prologue: stage K-tile 0 into buf0, first-use order ----
    STG_(0,         sA);                 // U1a: A rho 0-63   (rows 0-63)
    STG_(8192,      sA + 128 * LDA_);    // U1b: A rho 64-127 (rows 128-191)
    STG_(65536,     sB);                 // U2a: B rho 0-63
    STG_(65536+8192,  sB + 128 * LDB_);  // U2b
    STG_(65536+16384, sB + 32 * LDB_);   // U3a: B odd octants
    STG_(65536+24576, sB + 160 * LDB_);  // U3b
    STG_(16384,     sA + 64 * LDA_);     // U4a: A rho 128-191 (rows 64-127)
    STG_(24576,     sA + 192 * LDA_);    // U4b: A rho 192-255 (rows 192-255)
    VMW(4);
    wgbar();

    for (int kt = 0; kt < KT; ++kt){
        const unsigned rA = (unsigned)(kt & 1) * 32768u;
        const unsigned rB = 65536u + rA;
        const unsigned wA = (unsigned)((kt + 1) & 1) * 32768u;
        const unsigned wB = 65536u + wA;
        const unsigned short* pA = sA + (long)(kt + 1) * 64;
        const unsigned short* pB = sB + (long)(kt + 1) * 64;
        const bool more = (kt + 1 < KT);

        bf16x8 a0[4][2], bE[2][2], bO[2][2];

        // ================= PH1: quad (mq=0, nq=0) =================
        #pragma unroll
        for (int i = 0; i < 4; ++i){
            a0[i][0] = *(const bf16x8*)(lds + rA + aRow + i*2048 + pcl0);
            a0[i][1] = *(const bf16x8*)(lds + rA + aRow + i*2048 + pcl1);
        }
        #pragma unroll
        for (int j = 0; j < 2; ++j){
            bE[j][0] = *(const bf16x8*)(lds + rB + j*2048 + bRow + pcl0);
            bE[j][1] = *(const bf16x8*)(lds + rB + j*2048 + bRow + pcl1);
        }
        if (more){ STG_(wA, pA); STG_(wA + 8192, pA + 128 * LDA_); }
        wgbar();
        __builtin_amdgcn_s_setprio(1);
        #pragma unroll
        for (int i = 0; i < 4; ++i)
            #pragma unroll
            for (int j = 0; j < 2; ++j){
                acc[i][j] = __builtin_amdgcn_mfma_f32_16x16x32_bf16(a0[i][0], bE[j][0], acc[i][j], 0, 0, 0);
                acc[i][j] = __builtin_amdgcn_mfma_f32_16x16x32_bf16(a0[i][1], bE[j][1], acc[i][j], 0, 0, 0);
            }
        __builtin_amdgcn_s_setprio(0);
        if (more){ VMW(4); } else { VMW(2); }
        wgbar();

        // ================= PH2: quad (mq=0, nq=1) =================
        #pragma unroll
        for (int j = 0; j < 2; ++j){
            bO[j][0] = *(const bf16x8*)(lds + rB + 16384 + j*2048 + bRow + pcl0);
            bO[j][1] = *(const bf16x8*)(lds + rB + 16384 + j*2048 + bRow + pcl1);
        }
        if (more){ STG_(wB, pB); STG_(wB + 8192, pB + 128 * LDB_); }
        wgbar();
        __builtin_amdgcn_s_setprio(1);
        #pragma unroll
        for (int i = 0; i < 4; ++i)
            #pragma unroll
            for (int j = 0; j < 2; ++j){
                acc[i][2+j] = __builtin_amdgcn_mfma_f32_16x16x32_bf16(a0[i][0], bO[j][0], acc[i][2+j], 0, 0, 0);
                acc[i][2+j] = __builtin_amdgcn_mfma_f32_16x16x32_bf16(a0[i][1], bO[j][1], acc[i][2+j], 0, 0, 0);
            }
        __builtin_amdgcn_s_setprio(0);
        if (more){ VMW(4); } else { VMW(0); }
        wgbar();

        // ================= PH3: quad (mq=1, nq=0) =================
        #pragma unroll
        for (int i = 0; i < 4; ++i){
            a0[i][0] = *(const bf16x8*)(lds + rA + 16384 + aRow + i*2048 + pcl0);
            a0[i][1] = *(const bf16x8*)(lds + rA + 16384 + aRow + i*2048 + pcl1);
        }
        if (more){ STG_(wB + 16384, pB + 32 * LDB_); STG_(wB + 24576, pB + 160 * LDB_); }
        wgbar();
        __builtin_amdgcn_s_setprio(1);
        #pragma unroll
        for (int i = 0; i < 4; ++i)
            #pragma unroll
            for (int j = 0; j < 2; ++j){
                acc[4+i][j] = __builtin_amdgcn_mfma_f32_16x16x32_bf16(a0[i][0], bE[j][0], acc[4+i][j], 0, 0, 0);
                acc[4+i][j] = __builtin_amdgcn_mfma_f32_16x16x32_bf16(a0[i][1], bE[j][1], acc[4+i][j], 0, 0, 0);
            }
        __builtin_amdgcn_s_setprio(0);
        wgbar();                                  // no wait needed here

        // ================= PH4: quad (mq=1, nq=1) =================
        if (more){ STG_(wA + 16384, pA + 64 * LDA_); STG_(wA + 24576, pA + 192 * LDA_); }
        wgbar();
        __builtin_amdgcn_s_setprio(1);
        #pragma unroll
        for (int i = 0; i < 4; ++i)
            #pragma unroll
            for (int j = 0; j < 2; ++j){
                acc[4+i][2+j] = __builtin_amdgcn_mfma_f32_16x16x32_bf16(a0[i][0], bO[j][0], acc[4+i][2+j], 0, 0, 0);
                acc[4+i][2+j] = __builtin_amdgcn_mfma_f32_16x16x32_bf16(a0[i][1], bO[j][1], acc[4+i][2+j], 0, 0, 0);
            }
        __builtin_amdgcn_s_setprio(0);
        if (more){ VMW(4); }
        wgbar();
    }
#undef STG_

    // ---- epilogue: C write ----
    const int r0 = (lane >> 4) * 4;
    const int cc = lane & 15;
    const int Nn = nbx * 256;
    const float* bc = (EPI == 2) ? (biasA + (long)(m0 >> 12) * Nn) : nullptr;
    #pragma unroll
    for (int i = 0; i < 8; ++i){
        int rowb = m0 + wr*128 + i*16 + r0;
        int wdx[4];
        if (EPI == 2){
            #pragma unroll
            for (int r = 0; r < 4; ++r){
                int wv = widths[rowb + r];
                wdx[r] = (wv < 0) ? 0 : ((wv > 8) ? 8 : wv);
            }
        }
        #pragma unroll
        for (int j = 0; j < 4; ++j){
            int col = n0 + wc*64 + j*16 + cc;
            float cb = 0.f;
            if (EPI != 2 && biasA) cb = biasA[col];
            #pragma unroll
            for (int r = 0; r < 4; ++r){
                long o = (long)(rowb + r) * ldc + col;
                float v = acc[i][j][r] + cb;
                if (EPI == 2){
                    v += bc[col] + biasB[(long)wdx[r] * Nn + col];
                    v = fmaxf(v, 0.f);
                    ((unsigned short*)Cp)[o] = f2bf(v);
                } else {
                    ((float*)Cp)[o] = v;
                }
            }
        }
    }
}

// ---------------------------------------------------------------------------
extern "C" void kernel_launch(void* const* d_in, const int* in_sizes, int n_in,
                              void* d_out, int out_size, void* d_ws, size_t ws_size,
                              hipStream_t stream)
{
    const float* token_reps  = (const float*)d_in[0];
    const int*   span_ids    = (const int*)d_in[1];
    const void*  span_masks  = d_in[2];
    const float* cls_reps    = (const float*)d_in[3];
    const int*   span_widths = (const int*)d_in[4];
    const float* cls_emb     = (const float*)d_in[5];
    const float* in_proj_w   = (const float*)d_in[6];
    const float* in_proj_b   = (const float*)d_in[7];
    const float* out_proj_w  = (const float*)d_in[8];
    const float* out_proj_b  = (const float*)d_in[9];
    const float* width_table = (const float*)d_in[10];
    const float* w1          = (const float*)d_in[11];
    const float* b1          = (const float*)d_in[12];
    const float* w2          = (const float*)d_in[13];
    const float* b2          = (const float*)d_in[14];

    char* ws = (char*)d_ws;
    size_t off = 0;
    auto alloc = [&](size_t bytes)->char*{
        char* p = ws + off;
        off += (bytes + 255) & ~(size_t)255;
        return p;
    };
    int*            flag  = (int*)           alloc(4);
    float*          qbuf  = (float*)         alloc((size_t)H_ * 4);
    unsigned short* Xb    = (unsigned short*)alloc((size_t)ROWS_XP * H_ * 2);
    unsigned short* Wkv   = (unsigned short*)alloc((size_t)1536 * H_ * 2);
    float*          KV    = (float*)         alloc((size_t)ROWS_XP * 1536 * 4);
    float*          SC    = (float*)         alloc((size_t)B_ * NH_ * SP1 * 4);
    unsigned short* CTX   = (unsigned short*)alloc((size_t)NSPAN * H_ * 2);
    unsigned short* W1a   = (unsigned short*)alloc((size_t)INNER_ * H_ * 2);
    unsigned short* OutT  = (unsigned short*)alloc((size_t)H_ * H_ * 2);
    unsigned short* Wfuse = (unsigned short*)alloc((size_t)INNER_ * H_ * 2);
    unsigned short* W2b   = (unsigned short*)alloc((size_t)H_ * INNER_ * 2);
    unsigned short* H1    = (unsigned short*)alloc((size_t)NSPAN * INNER_ * 2);
    float*          BiasC = (float*)         alloc((size_t)B_ * INNER_ * 4);
    float*          WC    = (float*)         alloc((size_t)9 * INNER_ * 4);
    (void)ws_size; (void)in_sizes; (void)n_in; (void)out_size;

    // prep / conversions
    detect_mask_kernel<<<1, 256, 0, stream>>>((const unsigned*)span_masks, flag);
    build_x_kernel<<<ROWS_X, 256, 0, stream>>>(token_reps, cls_emb, Xb);
    conv_f32_bf16<<<512, 256, 0, stream>>>(in_proj_w + (size_t)768 * H_, Wkv, (long)(1536 * H_ / 4));
    conv_f32_bf16<<<512, 256, 0, stream>>>(w2, W2b, (long)(H_ * INNER_ / 4));
    conv_w1a_kernel<<<INNER_, 192, 0, stream>>>(w1, W1a);
    transconv_kernel<<<dim3(24, 24), 256, 0, stream>>>(out_proj_w, OutT);
    q_kernel<<<H_ / 4, 256, 0, stream>>>(cls_emb, in_proj_w, in_proj_b, qbuf);
    biasc_kernel<<<INNER_ / 4, 256, 0, stream>>>(w1, b1, out_proj_b, cls_reps, BiasC);
    wc_kernel<<<INNER_ / 4, 256, 0, stream>>>(w1, width_table, WC);

    // Wfused = W1a @ OutT^T   (3072x768, K=768)
    gemm97<1><<<(768/128) * (INNER_/128), 256, 0, stream>>>(
        W1a, OutT, nullptr, Wfuse, INNER_, 768, 768, 768, 768, 768, 768/128);

    // KV = X @ [wk;wv]^T + b   (2176x1536, K=768)
    gemm97<0><<<(1536/128) * (ROWS_XP/128), 256, 0, stream>>>(
        Xb, Wkv, in_proj_b + 768, KV, ROWS_XP, 1536, 768, 768, 768, 1536, 1536/128);

    scores_kernel<<<ROWS_X, 256, 0, stream>>>(qbuf, KV, SC);
    attn_kernel<<<NSPAN, 256, 0, stream>>>(span_ids, span_masks, flag, SC, KV, CTX);

    // H1 = relu(CTX @ Wfused^T + BiasC[b] + WC[width])   (16384x3072, K=768)
    gemm256<2, 768, 768><<<(INNER_/256) * (NSPAN/256), 512, 0, stream>>>(
        CTX, Wfuse, BiasC, WC, span_widths, H1, 768, INNER_, INNER_/256);

    // out = H1 @ w2^T + b2   (16384x768, K=3072) -> f32 d_out
    gemm256<0, 3072, 3072><<<(768/256) * (NSPAN/256), 512, 0, stream>>>(
        H1, W2b, b2, nullptr, nullptr, (float*)d_out, 3072, 768, 768/256);
}